// Round 1
// baseline (2019.988 us; speedup 1.0000x reference)
//
#include <hip/hip_runtime.h>

#define EL 512
#define NB 64
#define IMG (EL*EL)

// ---------------- complex helpers ----------------
__device__ __forceinline__ float2 cadd(float2 a, float2 b){ return make_float2(a.x+b.x, a.y+b.y); }
__device__ __forceinline__ float2 csub(float2 a, float2 b){ return make_float2(a.x-b.x, a.y-b.y); }
__device__ __forceinline__ float2 cmul(float2 a, float2 b){ return make_float2(a.x*b.x - a.y*b.y, a.x*b.y + a.y*b.x); }

template<int SIGN> __device__ __forceinline__ float2 mulW4(float2 a);
template<> __device__ __forceinline__ float2 mulW4<-1>(float2 a){ return make_float2( a.y, -a.x); } // * -i
template<> __device__ __forceinline__ float2 mulW4< 1>(float2 a){ return make_float2(-a.y,  a.x); } // * +i

// 8-point DFT, SIGN=-1 forward, +1 inverse (unnormalized)
template<int SIGN>
__device__ __forceinline__ void dft8(const float2* x, float2* X){
  float2 s04=cadd(x[0],x[4]), d04=csub(x[0],x[4]);
  float2 s26=cadd(x[2],x[6]), d26=csub(x[2],x[6]);
  float2 s15=cadd(x[1],x[5]), d15=csub(x[1],x[5]);
  float2 s37=cadd(x[3],x[7]), d37=csub(x[3],x[7]);
  float2 wd26 = mulW4<SIGN>(d26);
  float2 wd37 = mulW4<SIGN>(d37);
  float2 E0=cadd(s04,s26), E2=csub(s04,s26), E1=cadd(d04,wd26), E3=csub(d04,wd26);
  float2 O0=cadd(s15,s37), O2=csub(s15,s37), O1=cadd(d15,wd37), O3=csub(d15,wd37);
  const float C=0.70710678118654752440f;
  float2 w1 = make_float2(C, SIGN*C);
  float2 w3 = make_float2(-C, SIGN*C);
  float2 a1 = cmul(w1, O1);
  float2 a2 = mulW4<SIGN>(O2);
  float2 a3 = cmul(w3, O3);
  X[0]=cadd(E0,O0); X[4]=csub(E0,O0);
  X[1]=cadd(E1,a1); X[5]=csub(E1,a1);
  X[2]=cadd(E2,a2); X[6]=csub(E2,a2);
  X[3]=cadd(E3,a3); X[7]=csub(E3,a3);
}

// 512-point FFT by one wave (64 lanes). Input: v[a] = x[64*a + lane].
// Output: v[r] = X[8*lane + r]. buf: per-wave LDS scratch, >= 576 float2.
// __syncthreads used (all waves in the block call this uniformly).
template<int SIGN>
__device__ void fft512(float2 v[8], float2* buf, int lane){
  const float SGN = (float)SIGN;
  float sn, cs;
  float2 y[8];
  dft8<SIGN>(v, y);
  __sincosf(SGN * 0.012271846303085130f * (float)lane, &sn, &cs);   // 2pi/512
  {
    float2 w1 = make_float2(cs, sn), w = w1;
    #pragma unroll
    for (int r=1;r<8;++r){ y[r] = cmul(y[r], w); w = cmul(w, w1); }
  }
  __syncthreads();                       // protect vs previous phase reads (WAR)
  #pragma unroll
  for (int r=0;r<8;++r) buf[72*r + lane] = y[r];
  __syncthreads();
  int rA = lane >> 3, b2 = lane & 7;
  float2 g[8];
  #pragma unroll
  for (int a2=0;a2<8;++a2) g[a2] = buf[72*rA + 8*a2 + b2];
  float2 h[8];
  dft8<SIGN>(g, h);
  __sincosf(SGN * 0.098174770424681039f * (float)b2, &sn, &cs);     // 2pi/64
  {
    float2 u1 = make_float2(cs, sn), w = u1;
    #pragma unroll
    for (int r2=1;r2<8;++r2){ h[r2] = cmul(h[r2], w); w = cmul(w, u1); }
  }
  __syncthreads();                       // reads above done before overwrite
  #pragma unroll
  for (int r2=0;r2<8;++r2) buf[72*b2 + 9*r2 + rA] = h[r2];
  __syncthreads();
  int s2 = lane >> 3, r2l = lane & 7;
  __sincosf(SGN * 0.78539816339744831f * (float)s2, &sn, &cs);      // 2pi/8
  float2 ws2 = make_float2(cs, sn);
  float2 acc[8];
  #pragma unroll
  for (int r=0;r<8;++r) acc[r] = make_float2(0.f, 0.f);
  float2 coef = make_float2(1.f, 0.f);
  #pragma unroll
  for (int bb=0;bb<8;++bb){
    #pragma unroll
    for (int r=0;r<8;++r){
      acc[r] = cadd(acc[r], cmul(coef, buf[72*bb + 9*r2l + r]));    // broadcast reads
    }
    coef = cmul(coef, ws2);
  }
  #pragma unroll
  for (int r=0;r<8;++r) v[r] = acc[r];
}

// float <-> monotone uint for atomic min/max
__device__ __forceinline__ unsigned fenc(float f){
  unsigned u = __float_as_uint(f);
  return (u & 0x80000000u) ? ~u : (u | 0x80000000u);
}
__device__ __forceinline__ float fdec(unsigned e){
  return (e & 0x80000000u) ? __uint_as_float(e & 0x7FFFFFFFu) : __uint_as_float(~e);
}

// ---------------- kernels ----------------
__global__ void k_init(double* accum, unsigned* umin, unsigned* umax){
  int t = threadIdx.x;
  if (t == 0) *accum = 0.0;
  if (t < 2*NB){ umin[t] = 0xFFFFFFFFu; umax[t] = 0u; }
}

// rows: input -> copy to out left half, mf0, forward row FFT -> re/im planes
__global__ __launch_bounds__(256)
void k_row_fwd(const float* __restrict__ in0, const float* __restrict__ in1,
               float* __restrict__ re, float* __restrict__ im,
               float* __restrict__ outp, int base, int Pc){
  __shared__ float2 xbuf[4][576];
  int wave = threadIdx.x >> 6, lane = threadIdx.x & 63;
  int g = blockIdx.x >> 5;          // local image [0, 2*Pc)
  int rowblk = blockIdx.x & 31;
  bool isin = (g < Pc);
  int b = base + (isin ? g : g - Pc);
  const float* src = (isin ? in0 : in1) + (size_t)b * IMG;
  float* outhalf = outp + (isin ? (size_t)0 : (size_t)NB*EL*1024) + (size_t)b * EL * 1024;
  float* rp = re + (size_t)g * IMG;
  float* ip = im + (size_t)g * IMG;
  float2* buf = xbuf[wave];
  for (int i=0;i<4;++i){
    int yrow = rowblk*16 + wave*4 + i;
    const float* s = src + (size_t)yrow*EL;
    float2 v[8];
    #pragma unroll
    for (int a=0;a<8;++a){
      float xv = s[64*a + lane];
      outhalf[(size_t)yrow*1024 + 64*a + lane] = xv;   // concat left half = raw input
      float m = __expf(-8.0f * xv * xv);               // soft_equality(x,0,0.25)
      v[a] = make_float2(m, 0.f);
    }
    fft512<-1>(v, buf, lane);
    float* rr = rp + (size_t)yrow*EL + 8*lane;
    float* ii = ip + (size_t)yrow*EL + 8*lane;
    *(float4*)rr     = make_float4(v[0].x, v[1].x, v[2].x, v[3].x);
    *(float4*)(rr+4) = make_float4(v[4].x, v[5].x, v[6].x, v[7].x);
    *(float4*)ii     = make_float4(v[0].y, v[1].y, v[2].y, v[3].y);
    *(float4*)(ii+4) = make_float4(v[4].y, v[5].y, v[6].y, v[7].y);
  }
}

// columns: fwd FFT -> |F|^2 -> inverse FFT, in a 8col x 512row LDS tile
__global__ __launch_bounds__(128)
void k_col(float* __restrict__ re, float* __restrict__ im){
  __shared__ float tre[8*516];
  __shared__ float tim[8*516];
  __shared__ float2 xbuf[2][576];
  int l = threadIdx.x;
  int wave = l >> 6, lane = l & 63;
  int g = blockIdx.x >> 6;
  int t = blockIdx.x & 63;
  int c0 = t*8;
  float* RP = re + (size_t)g*IMG;
  float* IP = im + (size_t)g*IMG;
  {
    int cq = (l & 1) * 4;
    int rb = l >> 1;
    for (int it=0; it<8; ++it){
      int r = rb + it*64;
      float4 vr = *(const float4*)(RP + (size_t)r*EL + c0 + cq);
      float4 vi = *(const float4*)(IP + (size_t)r*EL + c0 + cq);
      tre[(cq+0)*516 + r] = vr.x; tre[(cq+1)*516 + r] = vr.y;
      tre[(cq+2)*516 + r] = vr.z; tre[(cq+3)*516 + r] = vr.w;
      tim[(cq+0)*516 + r] = vi.x; tim[(cq+1)*516 + r] = vi.y;
      tim[(cq+2)*516 + r] = vi.z; tim[(cq+3)*516 + r] = vi.w;
    }
  }
  __syncthreads();
  float2* buf = xbuf[wave];
  for (int cc=0; cc<4; ++cc){
    int c = wave*4 + cc;
    float2 v[8];
    #pragma unroll
    for (int a=0;a<8;++a)
      v[a] = make_float2(tre[c*516 + 64*a + lane], tim[c*516 + 64*a + lane]);
    fft512<-1>(v, buf, lane);
    float* ps = (float*)buf;
    __syncthreads();   // stage-C reads of fwd FFT done before ps overwrite
    {
      float p0=v[0].x*v[0].x+v[0].y*v[0].y, p1=v[1].x*v[1].x+v[1].y*v[1].y;
      float p2=v[2].x*v[2].x+v[2].y*v[2].y, p3=v[3].x*v[3].x+v[3].y*v[3].y;
      float p4=v[4].x*v[4].x+v[4].y*v[4].y, p5=v[5].x*v[5].x+v[5].y*v[5].y;
      float p6=v[6].x*v[6].x+v[6].y*v[6].y, p7=v[7].x*v[7].x+v[7].y*v[7].y;
      *(float4*)(ps + 8*lane)     = make_float4(p0,p1,p2,p3);
      *(float4*)(ps + 8*lane + 4) = make_float4(p4,p5,p6,p7);
    }
    __syncthreads();
    float2 v2[8];
    #pragma unroll
    for (int a=0;a<8;++a) v2[a] = make_float2(ps[64*a + lane], 0.f);
    fft512<1>(v2, buf, lane);
    *(float4*)(&tre[c*516 + 8*lane])     = make_float4(v2[0].x, v2[1].x, v2[2].x, v2[3].x);
    *(float4*)(&tre[c*516 + 8*lane + 4]) = make_float4(v2[4].x, v2[5].x, v2[6].x, v2[7].x);
    *(float4*)(&tim[c*516 + 8*lane])     = make_float4(v2[0].y, v2[1].y, v2[2].y, v2[3].y);
    *(float4*)(&tim[c*516 + 8*lane + 4]) = make_float4(v2[4].y, v2[5].y, v2[6].y, v2[7].y);
  }
  __syncthreads();
  {
    int cq = (l & 1) * 4;
    int rb = l >> 1;
    for (int it=0; it<8; ++it){
      int r = rb + it*64;
      float4 vr = make_float4(tre[(cq+0)*516+r], tre[(cq+1)*516+r], tre[(cq+2)*516+r], tre[(cq+3)*516+r]);
      float4 vi = make_float4(tim[(cq+0)*516+r], tim[(cq+1)*516+r], tim[(cq+2)*516+r], tim[(cq+3)*516+r]);
      *(float4*)(RP + (size_t)r*EL + c0 + cq) = vr;
      *(float4*)(IP + (size_t)r*EL + c0 + cq) = vi;
    }
  }
}

// rows: inverse FFT -> real ac (scaled), in-place into re plane; fused min/max
__global__ __launch_bounds__(256)
void k_row_inv(float* __restrict__ re, const float* __restrict__ im,
               unsigned* __restrict__ umin, unsigned* __restrict__ umax,
               int base, int Pc){
  __shared__ float2 xbuf[4][576];
  __shared__ float redmn[4], redmx[4];
  int wave = threadIdx.x >> 6, lane = threadIdx.x & 63;
  int g = blockIdx.x >> 5;
  int rowblk = blockIdx.x & 31;
  float* rp = re + (size_t)g*IMG;
  const float* ip = im + (size_t)g*IMG;
  float2* buf = xbuf[wave];
  const float SCALE = 1.0f / 68719476736.0f;   // 2^-36 : 1/(N^2) ifft2 norm * 1/(el*el) power norm
  float mn = 3.4e38f, mx = -3.4e38f;
  for (int i=0;i<4;++i){
    int yrow = rowblk*16 + wave*4 + i;
    float2 v[8];
    #pragma unroll
    for (int a=0;a<8;++a)
      v[a] = make_float2(rp[(size_t)yrow*EL + 64*a + lane], ip[(size_t)yrow*EL + 64*a + lane]);
    fft512<1>(v, buf, lane);
    float o[8];
    #pragma unroll
    for (int r=0;r<8;++r){ o[r] = v[r].x * SCALE; mn = fminf(mn, o[r]); mx = fmaxf(mx, o[r]); }
    float* rr = rp + (size_t)yrow*EL + 8*lane;
    *(float4*)rr     = make_float4(o[0],o[1],o[2],o[3]);
    *(float4*)(rr+4) = make_float4(o[4],o[5],o[6],o[7]);
  }
  for (int off=32; off>0; off>>=1){
    mn = fminf(mn, __shfl_down(mn, off, 64));
    mx = fmaxf(mx, __shfl_down(mx, off, 64));
  }
  if (lane==0){ redmn[wave]=mn; redmx[wave]=mx; }
  __syncthreads();
  if (threadIdx.x==0){
    mn = fminf(fminf(redmn[0],redmn[1]), fminf(redmn[2],redmn[3]));
    mx = fmaxf(fmaxf(redmx[0],redmx[1]), fmaxf(redmx[2],redmx[3]));
    int gid = (g < Pc) ? (base + g) : (NB + base + g - Pc);
    atomicMin(&umin[gid], fenc(mn));
    atomicMax(&umax[gid], fenc(mx));
  }
}

// shift + normalize + mask + write right halves + MSE accumulation
__global__ __launch_bounds__(256)
void k_final(const float* __restrict__ re, const unsigned* __restrict__ umin,
             const unsigned* __restrict__ umax, float* __restrict__ outp,
             double* __restrict__ accum, int base, int Pc){
  __shared__ float red[4];
  size_t idx = (size_t)blockIdx.x * 256 + threadIdx.x;
  int x  = (int)(idx & 511);
  int y  = (int)((idx >> 9) & 511);
  int bl = (int)(idx >> 18);
  int b = base + bl;
  int sy = (y + 256) & 511, sx = (x + 256) & 511;
  float aci = re[(size_t)bl*IMG + (size_t)sy*EL + sx];
  float act = re[(size_t)(Pc + bl)*IMG + (size_t)sy*EL + sx];
  float mni = fdec(umin[b]),      mxi = fdec(umax[b]);
  float mnt = fdec(umin[NB + b]), mxt = fdec(umax[NB + b]);
  float dx = (float)(x - 256), dy = (float)(y - 256);
  float mask = __expf(-(dx*dx + dy*dy) * 0.00125f);    // 1/(2*20^2)
  float ia = (aci - mni) / (mxi - mni + 1e-12f) * mask;
  float ta = (act - mnt) / (mxt - mnt + 1e-12f) * mask;
  size_t rowo = ((size_t)b * 512 + (size_t)y) * 1024 + 512 + x;
  outp[rowo] = ia;
  outp[(size_t)NB*512*1024 + rowo] = ta;
  float d = ia - ta; d = d*d;
  for (int off=32; off>0; off>>=1) d += __shfl_down(d, off, 64);
  int wave = threadIdx.x>>6, lane = threadIdx.x&63;
  if (lane==0) red[wave]=d;
  __syncthreads();
  if (threadIdx.x==0) atomicAdd(accum, (double)(red[0]+red[1]+red[2]+red[3]));
}

__global__ void k_div(const double* accum, float* out0){
  out0[0] = (float)(*accum / 16777216.0);   // mean over 64*512*512
}

// ---------------- launch ----------------
extern "C" void kernel_launch(void* const* d_in, const int* in_sizes, int n_in,
                              void* d_out, int out_size, void* d_ws, size_t ws_size,
                              hipStream_t stream){
  (void)in_sizes; (void)n_in; (void)out_size;
  const float* in0 = (const float*)d_in[0];
  const float* in1 = (const float*)d_in[1];
  float* out = (float*)d_out;
  char* ws = (char*)d_ws;
  double*   accum = (double*)ws;
  unsigned* umin  = (unsigned*)(ws + 512);
  unsigned* umax  = (unsigned*)(ws + 1024);
  float*    planes = (float*)(ws + 4096);

  size_t avail = ws_size > 4096 ? ws_size - 4096 : 0;
  int P = (int)(avail / (4ull * 1024ull * 1024ull));  // 4 MB per image-pair (re+im, in+tgt)
  if (P > NB) P = NB;
  if (P < 1)  P = 1;

  k_init<<<dim3(1), dim3(128), 0, stream>>>(accum, umin, umax);
  float* out1 = out + 1;
  for (int base = 0; base < NB; base += P){
    int Pc = (NB - base < P) ? (NB - base) : P;
    float* re = planes;
    float* im = planes + (size_t)2 * Pc * IMG;
    k_row_fwd<<<dim3(2*Pc*32), dim3(256), 0, stream>>>(in0, in1, re, im, out1, base, Pc);
    k_col    <<<dim3(2*Pc*64), dim3(128), 0, stream>>>(re, im);
    k_row_inv<<<dim3(2*Pc*32), dim3(256), 0, stream>>>(re, im, umin, umax, base, Pc);
    k_final  <<<dim3(Pc*1024), dim3(256), 0, stream>>>(re, umin, umax, out1, accum, base, Pc);
  }
  k_div<<<dim3(1), dim3(1), 0, stream>>>(accum, out);
}

// Round 2
// 808.436 us; speedup vs baseline: 2.4986x; 2.4986x over previous
//
#include <hip/hip_runtime.h>

#define EL 512
#define NB 64
#define IMG (EL*EL)

// ---------------- complex helpers ----------------
__device__ __forceinline__ float2 cadd(float2 a, float2 b){ return make_float2(a.x+b.x, a.y+b.y); }
__device__ __forceinline__ float2 csub(float2 a, float2 b){ return make_float2(a.x-b.x, a.y-b.y); }
__device__ __forceinline__ float2 cmul(float2 a, float2 b){ return make_float2(a.x*b.x - a.y*b.y, a.x*b.y + a.y*b.x); }

template<int SIGN> __device__ __forceinline__ float2 mulW4(float2 a);
template<> __device__ __forceinline__ float2 mulW4<-1>(float2 a){ return make_float2( a.y, -a.x); } // * -i
template<> __device__ __forceinline__ float2 mulW4< 1>(float2 a){ return make_float2(-a.y,  a.x); } // * +i

// 8-point DFT, SIGN=-1 forward, +1 inverse (unnormalized)
template<int SIGN>
__device__ __forceinline__ void dft8(const float2* x, float2* X){
  float2 s04=cadd(x[0],x[4]), d04=csub(x[0],x[4]);
  float2 s26=cadd(x[2],x[6]), d26=csub(x[2],x[6]);
  float2 s15=cadd(x[1],x[5]), d15=csub(x[1],x[5]);
  float2 s37=cadd(x[3],x[7]), d37=csub(x[3],x[7]);
  float2 wd26 = mulW4<SIGN>(d26);
  float2 wd37 = mulW4<SIGN>(d37);
  float2 E0=cadd(s04,s26), E2=csub(s04,s26), E1=cadd(d04,wd26), E3=csub(d04,wd26);
  float2 O0=cadd(s15,s37), O2=csub(s15,s37), O1=cadd(d15,wd37), O3=csub(d15,wd37);
  const float C=0.70710678118654752440f;
  float2 w1 = make_float2(C, SIGN*C);
  float2 w3 = make_float2(-C, SIGN*C);
  float2 a1 = cmul(w1, O1);
  float2 a2 = mulW4<SIGN>(O2);
  float2 a3 = cmul(w3, O3);
  X[0]=cadd(E0,O0); X[4]=csub(E0,O0);
  X[1]=cadd(E1,a1); X[5]=csub(E1,a1);
  X[2]=cadd(E2,a2); X[6]=csub(E2,a2);
  X[3]=cadd(E3,a3); X[7]=csub(E3,a3);
}

// 512-point FFT by one wave (64 lanes), radix-8^3 DIF.
// In:  v[a] = x[64*a + lane].  Out: v[a] = X[64*a + lane]  (same layout!)
// buf: per-wave LDS scratch, >= 648 float2. Uses __syncthreads (all waves
// in the block must call uniformly).
template<int SIGN>
__device__ void fft512(float2 v[8], float2* buf, int lane){
  const float SGN = (float)SIGN;
  float sn, cs;
  float2 y[8];
  dft8<SIGN>(v, y);                          // over n2 -> k0
  __sincosf(SGN * 0.012271846303085130f * (float)lane, &sn, &cs);   // 2pi/512
  {
    float2 w1 = make_float2(cs, sn), w = w1; // W512^(lane*k0) = W64^(n1 k0) * W512^(n0 k0)
    #pragma unroll
    for (int r=1;r<8;++r){ y[r] = cmul(y[r], w); w = cmul(w, w1); }
  }
  __syncthreads();                           // WAR vs previous phase reads
  #pragma unroll
  for (int r=0;r<8;++r) buf[72*r + lane] = y[r];
  __syncthreads();
  int k0 = lane >> 3, n0 = lane & 7;         // new lane = 8*k0 + n0
  float2 g[8];
  #pragma unroll
  for (int n1=0;n1<8;++n1) g[n1] = buf[72*k0 + 8*n1 + n0];
  float2 h[8];
  dft8<SIGN>(g, h);                          // over n1 -> k1
  __sincosf(SGN * 0.098174770424681039f * (float)n0, &sn, &cs);     // 2pi/64
  {
    float2 u1 = make_float2(cs, sn), w = u1; // W64^(n0*k1)
    #pragma unroll
    for (int r=1;r<8;++r){ h[r] = cmul(h[r], w); w = cmul(w, u1); }
  }
  __syncthreads();
  #pragma unroll
  for (int r=0;r<8;++r) buf[72*n0 + 9*k0 + r] = h[r];
  __syncthreads();
  int k0r = lane & 7, k1r = lane >> 3;       // final lane = 8*k1 + k0
  float2 g2[8];
  #pragma unroll
  for (int m=0;m<8;++m) g2[m] = buf[72*m + 9*k0r + k1r];
  dft8<SIGN>(g2, v);                         // over n0 -> k2 ; X[64*k2 + 8*k1 + k0]
}

// float <-> monotone uint for atomic min/max
__device__ __forceinline__ unsigned fenc(float f){
  unsigned u = __float_as_uint(f);
  return (u & 0x80000000u) ? ~u : (u | 0x80000000u);
}
__device__ __forceinline__ float fdec(unsigned e){
  return (e & 0x80000000u) ? __uint_as_float(e & 0x7FFFFFFFu) : __uint_as_float(~e);
}

// ---------------- kernels ----------------
__global__ void k_init(double* accum, unsigned* umin, unsigned* umax){
  int t = threadIdx.x;
  if (t == 0) *accum = 0.0;
  if (t < 2*NB){ umin[t] = 0xFFFFFFFFu; umax[t] = 0u; }
}

// rows: input -> copy to out left half, mf0, forward row FFT -> re/im planes
__global__ __launch_bounds__(256)
void k_row_fwd(const float* __restrict__ in0, const float* __restrict__ in1,
               float* __restrict__ re, float* __restrict__ im,
               float* __restrict__ outp, int base, int Pc){
  __shared__ float2 xbuf[4][648];
  int wave = threadIdx.x >> 6, lane = threadIdx.x & 63;
  int g = blockIdx.x >> 5;          // local image [0, 2*Pc)
  int rowblk = blockIdx.x & 31;
  bool isin = (g < Pc);
  int b = base + (isin ? g : g - Pc);
  const float* src = (isin ? in0 : in1) + (size_t)b * IMG;
  float* outhalf = outp + (isin ? (size_t)0 : (size_t)NB*EL*1024) + (size_t)b * EL * 1024;
  float* rp = re + (size_t)g * IMG;
  float* ip = im + (size_t)g * IMG;
  float2* buf = xbuf[wave];
  for (int i=0;i<4;++i){
    int yrow = rowblk*16 + wave*4 + i;
    const float* s = src + (size_t)yrow*EL;
    float2 v[8];
    #pragma unroll
    for (int a=0;a<8;++a){
      float xv = s[64*a + lane];
      outhalf[(size_t)yrow*1024 + 64*a + lane] = xv;   // concat left half = raw input
      float m = __expf(-8.0f * xv * xv);               // soft_equality(x,0,0.25)
      v[a] = make_float2(m, 0.f);
    }
    fft512<-1>(v, buf, lane);
    #pragma unroll
    for (int a=0;a<8;++a){
      rp[(size_t)yrow*EL + 64*a + lane] = v[a].x;      // natural order, 256B coalesced
      ip[(size_t)yrow*EL + 64*a + lane] = v[a].y;
    }
  }
}

// columns: fwd FFT -> |F|^2 (registers) -> inverse FFT, 8col x 512row LDS tile
__global__ __launch_bounds__(128)
void k_col(float* __restrict__ re, float* __restrict__ im){
  __shared__ float tre[8*516];
  __shared__ float tim[8*516];
  __shared__ float2 xbuf[2][648];
  int l = threadIdx.x;
  int wave = l >> 6, lane = l & 63;
  int g = blockIdx.x >> 6;
  int t = blockIdx.x & 63;
  int c0 = t*8;
  float* RP = re + (size_t)g*IMG;
  float* IP = im + (size_t)g*IMG;
  {
    int cq = (l & 1) * 4;
    int rb = l >> 1;
    for (int it=0; it<8; ++it){
      int r = rb + it*64;
      float4 vr = *(const float4*)(RP + (size_t)r*EL + c0 + cq);
      float4 vi = *(const float4*)(IP + (size_t)r*EL + c0 + cq);
      tre[(cq+0)*516 + r] = vr.x; tre[(cq+1)*516 + r] = vr.y;
      tre[(cq+2)*516 + r] = vr.z; tre[(cq+3)*516 + r] = vr.w;
      tim[(cq+0)*516 + r] = vi.x; tim[(cq+1)*516 + r] = vi.y;
      tim[(cq+2)*516 + r] = vi.z; tim[(cq+3)*516 + r] = vi.w;
    }
  }
  __syncthreads();
  float2* buf = xbuf[wave];
  for (int cc=0; cc<4; ++cc){
    int c = wave*4 + cc;
    float2 v[8];
    #pragma unroll
    for (int a=0;a<8;++a)
      v[a] = make_float2(tre[c*516 + 64*a + lane], tim[c*516 + 64*a + lane]);
    fft512<-1>(v, buf, lane);
    #pragma unroll
    for (int a=0;a<8;++a)
      v[a] = make_float2(v[a].x*v[a].x + v[a].y*v[a].y, 0.f);  // |F|^2, layout-compatible
    fft512<1>(v, buf, lane);
    #pragma unroll
    for (int a=0;a<8;++a){
      tre[c*516 + 64*a + lane] = v[a].x;
      tim[c*516 + 64*a + lane] = v[a].y;
    }
  }
  __syncthreads();
  {
    int cq = (l & 1) * 4;
    int rb = l >> 1;
    for (int it=0; it<8; ++it){
      int r = rb + it*64;
      float4 vr = make_float4(tre[(cq+0)*516+r], tre[(cq+1)*516+r], tre[(cq+2)*516+r], tre[(cq+3)*516+r]);
      float4 vi = make_float4(tim[(cq+0)*516+r], tim[(cq+1)*516+r], tim[(cq+2)*516+r], tim[(cq+3)*516+r]);
      *(float4*)(RP + (size_t)r*EL + c0 + cq) = vr;
      *(float4*)(IP + (size_t)r*EL + c0 + cq) = vi;
    }
  }
}

// rows: inverse FFT -> real ac (scaled), in-place into re plane; fused min/max
__global__ __launch_bounds__(256)
void k_row_inv(float* __restrict__ re, const float* __restrict__ im,
               unsigned* __restrict__ umin, unsigned* __restrict__ umax,
               int base, int Pc){
  __shared__ float2 xbuf[4][648];
  __shared__ float redmn[4], redmx[4];
  int wave = threadIdx.x >> 6, lane = threadIdx.x & 63;
  int g = blockIdx.x >> 5;
  int rowblk = blockIdx.x & 31;
  float* rp = re + (size_t)g*IMG;
  const float* ip = im + (size_t)g*IMG;
  float2* buf = xbuf[wave];
  const float SCALE = 1.0f / 68719476736.0f;   // 2^-36 : ifft2 norm * 1/(el*el) power norm
  float mn = 3.4e38f, mx = -3.4e38f;
  for (int i=0;i<4;++i){
    int yrow = rowblk*16 + wave*4 + i;
    float2 v[8];
    #pragma unroll
    for (int a=0;a<8;++a)
      v[a] = make_float2(rp[(size_t)yrow*EL + 64*a + lane], ip[(size_t)yrow*EL + 64*a + lane]);
    fft512<1>(v, buf, lane);
    #pragma unroll
    for (int a=0;a<8;++a){
      float o = v[a].x * SCALE;
      mn = fminf(mn, o); mx = fmaxf(mx, o);
      rp[(size_t)yrow*EL + 64*a + lane] = o;     // in-place, natural order
    }
  }
  for (int off=32; off>0; off>>=1){
    mn = fminf(mn, __shfl_down(mn, off, 64));
    mx = fmaxf(mx, __shfl_down(mx, off, 64));
  }
  if (lane==0){ redmn[wave]=mn; redmx[wave]=mx; }
  __syncthreads();
  if (threadIdx.x==0){
    mn = fminf(fminf(redmn[0],redmn[1]), fminf(redmn[2],redmn[3]));
    mx = fmaxf(fmaxf(redmx[0],redmx[1]), fmaxf(redmx[2],redmx[3]));
    int gid = (g < Pc) ? (base + g) : (NB + base + g - Pc);
    atomicMin(&umin[gid], fenc(mn));
    atomicMax(&umax[gid], fenc(mx));
  }
}

// shift + normalize + mask + write right halves + MSE accumulation
// grid = Pc*32 blocks; each block: one image pair slice of 16 rows, float4.
__global__ __launch_bounds__(256)
void k_final(const float* __restrict__ re, const unsigned* __restrict__ umin,
             const unsigned* __restrict__ umax, float* __restrict__ outp,
             double* __restrict__ accum, int base, int Pc){
  __shared__ float red[4];
  int g    = blockIdx.x >> 5;      // local pair index [0,Pc)
  int part = blockIdx.x & 31;      // 16-row slice
  int b = base + g;
  float mni = fdec(umin[b]),      mxi = fdec(umax[b]);
  float mnt = fdec(umin[NB + b]), mxt = fdec(umax[NB + b]);
  float inv_i = 1.0f / (mxi - mni + 1e-12f);
  float inv_t = 1.0f / (mxt - mnt + 1e-12f);
  const float* ri = re + (size_t)g * IMG;
  const float* rt = re + (size_t)(Pc + g) * IMG;
  float* o_i = outp;
  float* o_t = outp + (size_t)NB * 512 * 1024;
  float acc = 0.f;
  for (int it=0; it<8; ++it){
    int q = it*256 + threadIdx.x;        // [0,2048)
    int y = part*16 + (q >> 7);
    int x = (q & 127) * 4;
    int sy = (y + 256) & 511, sx = (x + 256) & 511;   // sx stays 4-aligned contiguous
    float4 ai = *(const float4*)(ri + (size_t)sy*EL + sx);
    float4 at = *(const float4*)(rt + (size_t)sy*EL + sx);
    float dy = (float)(y - 256); float dy2 = dy*dy;
    float dx0 = (float)(x - 256);
    float m0 = __expf(-((dx0+0)*(dx0+0) + dy2) * 0.00125f);
    float m1 = __expf(-((dx0+1)*(dx0+1) + dy2) * 0.00125f);
    float m2 = __expf(-((dx0+2)*(dx0+2) + dy2) * 0.00125f);
    float m3 = __expf(-((dx0+3)*(dx0+3) + dy2) * 0.00125f);
    float4 oi, ot;
    oi.x = (ai.x - mni)*inv_i*m0; ot.x = (at.x - mnt)*inv_t*m0;
    oi.y = (ai.y - mni)*inv_i*m1; ot.y = (at.y - mnt)*inv_t*m1;
    oi.z = (ai.z - mni)*inv_i*m2; ot.z = (at.z - mnt)*inv_t*m2;
    oi.w = (ai.w - mni)*inv_i*m3; ot.w = (at.w - mnt)*inv_t*m3;
    size_t rowo = ((size_t)b * 512 + (size_t)y) * 1024 + 512 + x;
    *(float4*)(o_i + 1 + rowo) = oi;   // +1: out[0] is the scalar loss
    *(float4*)(o_t + 1 + rowo) = ot;
    float d0 = oi.x - ot.x, d1 = oi.y - ot.y, d2 = oi.z - ot.z, d3 = oi.w - ot.w;
    acc += d0*d0 + d1*d1 + d2*d2 + d3*d3;
  }
  for (int off=32; off>0; off>>=1) acc += __shfl_down(acc, off, 64);
  int wave = threadIdx.x>>6, lane = threadIdx.x&63;
  if (lane==0) red[wave]=acc;
  __syncthreads();
  if (threadIdx.x==0) atomicAdd(accum, (double)(red[0]+red[1]+red[2]+red[3]));
}

__global__ void k_div(const double* accum, float* out0){
  out0[0] = (float)(*accum / 16777216.0);   // mean over 64*512*512
}

// ---------------- launch ----------------
extern "C" void kernel_launch(void* const* d_in, const int* in_sizes, int n_in,
                              void* d_out, int out_size, void* d_ws, size_t ws_size,
                              hipStream_t stream){
  (void)in_sizes; (void)n_in; (void)out_size;
  const float* in0 = (const float*)d_in[0];
  const float* in1 = (const float*)d_in[1];
  float* out = (float*)d_out;
  char* ws = (char*)d_ws;
  double*   accum = (double*)ws;
  unsigned* umin  = (unsigned*)(ws + 512);
  unsigned* umax  = (unsigned*)(ws + 1024);
  float*    planes = (float*)(ws + 4096);

  size_t avail = ws_size > 4096 ? ws_size - 4096 : 0;
  int P = (int)(avail / (4ull * 1024ull * 1024ull));  // 4 MB per image-pair (re+im, in+tgt)
  if (P > NB) P = NB;
  if (P < 1)  P = 1;

  k_init<<<dim3(1), dim3(128), 0, stream>>>(accum, umin, umax);
  float* out1 = out + 1;
  for (int base = 0; base < NB; base += P){
    int Pc = (NB - base < P) ? (NB - base) : P;
    float* re = planes;
    float* im = planes + (size_t)2 * Pc * IMG;
    k_row_fwd<<<dim3(2*Pc*32), dim3(256), 0, stream>>>(in0, in1, re, im, out1, base, Pc);
    k_col    <<<dim3(2*Pc*64), dim3(128), 0, stream>>>(re, im);
    k_row_inv<<<dim3(2*Pc*32), dim3(256), 0, stream>>>(re, im, umin, umax, base, Pc);
    k_final  <<<dim3(Pc*32),   dim3(256), 0, stream>>>(re, umin, umax, out, accum, base, Pc);
  }
  k_div<<<dim3(1), dim3(1), 0, stream>>>(accum, out);
}

// Round 3
// 679.571 us; speedup vs baseline: 2.9724x; 1.1896x over previous
//
#include <hip/hip_runtime.h>

#define EL 512
#define NB 64
#define IMG (EL*EL)

__device__ __forceinline__ void sb(){ __builtin_amdgcn_sched_barrier(0); }

// ---------------- complex helpers ----------------
__device__ __forceinline__ float2 cadd(float2 a, float2 b){ return make_float2(a.x+b.x, a.y+b.y); }
__device__ __forceinline__ float2 csub(float2 a, float2 b){ return make_float2(a.x-b.x, a.y-b.y); }
__device__ __forceinline__ float2 cmul(float2 a, float2 b){ return make_float2(a.x*b.x - a.y*b.y, a.x*b.y + a.y*b.x); }

template<int SIGN> __device__ __forceinline__ float2 mulW4(float2 a);
template<> __device__ __forceinline__ float2 mulW4<-1>(float2 a){ return make_float2( a.y, -a.x); } // * -i
template<> __device__ __forceinline__ float2 mulW4< 1>(float2 a){ return make_float2(-a.y,  a.x); } // * +i

// 8-point DFT, SIGN=-1 forward, +1 inverse (unnormalized)
template<int SIGN>
__device__ __forceinline__ void dft8(const float2* x, float2* X){
  float2 s04=cadd(x[0],x[4]), d04=csub(x[0],x[4]);
  float2 s26=cadd(x[2],x[6]), d26=csub(x[2],x[6]);
  float2 s15=cadd(x[1],x[5]), d15=csub(x[1],x[5]);
  float2 s37=cadd(x[3],x[7]), d37=csub(x[3],x[7]);
  float2 wd26 = mulW4<SIGN>(d26);
  float2 wd37 = mulW4<SIGN>(d37);
  float2 E0=cadd(s04,s26), E2=csub(s04,s26), E1=cadd(d04,wd26), E3=csub(d04,wd26);
  float2 O0=cadd(s15,s37), O2=csub(s15,s37), O1=cadd(d15,wd37), O3=csub(d15,wd37);
  const float C=0.70710678118654752440f;
  float2 w1 = make_float2(C, SIGN*C);
  float2 w3 = make_float2(-C, SIGN*C);
  float2 a1 = cmul(w1, O1);
  float2 a2 = mulW4<SIGN>(O2);
  float2 a3 = cmul(w3, O3);
  X[0]=cadd(E0,O0); X[4]=csub(E0,O0);
  X[1]=cadd(E1,a1); X[5]=csub(E1,a1);
  X[2]=cadd(E2,a2); X[6]=csub(E2,a2);
  X[3]=cadd(E3,a3); X[7]=csub(E3,a3);
}

// 512-point FFT by one wave (64 lanes), radix-8^3 DIF.
// In:  v[a] = x[64*a + lane].  Out: v[a] = X[64*a + lane]  (same layout)
// buf: WAVE-PRIVATE LDS scratch, >= 576 float2. No inter-wave sync needed:
// per-wave DS ops execute in order at HW level; sched_barrier(0) fences
// compiler code motion across the exchange phases.
template<int SIGN>
__device__ void fft512(float2 v[8], float2* buf, int lane){
  const float SGN = (float)SIGN;
  float sn, cs;
  float2 y[8];
  dft8<SIGN>(v, y);                          // over n2 -> k0
  __sincosf(SGN * 0.012271846303085130f * (float)lane, &sn, &cs);   // 2pi/512
  {
    float2 w1 = make_float2(cs, sn), w = w1;
    #pragma unroll
    for (int r=1;r<8;++r){ y[r] = cmul(y[r], w); w = cmul(w, w1); }
  }
  sb();
  #pragma unroll
  for (int r=0;r<8;++r) buf[72*r + lane] = y[r];
  sb();
  int k0 = lane >> 3, n0 = lane & 7;         // new lane = 8*k0 + n0
  float2 g[8];
  #pragma unroll
  for (int n1=0;n1<8;++n1) g[n1] = buf[72*k0 + 8*n1 + n0];
  float2 h[8];
  dft8<SIGN>(g, h);                          // over n1 -> k1
  __sincosf(SGN * 0.098174770424681039f * (float)n0, &sn, &cs);     // 2pi/64
  {
    float2 u1 = make_float2(cs, sn), w = u1;
    #pragma unroll
    for (int r=1;r<8;++r){ h[r] = cmul(h[r], w); w = cmul(w, u1); }
  }
  sb();
  #pragma unroll
  for (int r=0;r<8;++r) buf[72*n0 + 9*k0 + r] = h[r];
  sb();
  int k0r = lane & 7, k1r = lane >> 3;       // final lane = 8*k1 + k0
  float2 g2[8];
  #pragma unroll
  for (int m=0;m<8;++m) g2[m] = buf[72*m + 9*k0r + k1r];
  dft8<SIGN>(g2, v);                         // over n0 -> k2
}

// float <-> monotone uint for atomic min/max
__device__ __forceinline__ unsigned fenc(float f){
  unsigned u = __float_as_uint(f);
  return (u & 0x80000000u) ? ~u : (u | 0x80000000u);
}
__device__ __forceinline__ float fdec(unsigned e){
  return (e & 0x80000000u) ? __uint_as_float(e & 0x7FFFFFFFu) : __uint_as_float(~e);
}

// ---------------- kernels ----------------
__global__ void k_init(double* accum, unsigned* umin, unsigned* umax){
  int t = threadIdx.x;
  if (t == 0) *accum = 0.0;
  if (t < 2*NB){ umin[t] = 0xFFFFFFFFu; umax[t] = 0u; }
}

// rows: input -> copy to out left half, mf0, forward row FFT -> interleaved cplx
__global__ __launch_bounds__(256)
void k_row_fwd(const float* __restrict__ in0, const float* __restrict__ in1,
               float2* __restrict__ cplx, float* __restrict__ outp,
               int base, int Pc){
  __shared__ float2 xbuf[4][576];
  int wave = threadIdx.x >> 6, lane = threadIdx.x & 63;
  int g = blockIdx.x >> 5;          // local image [0, 2*Pc)
  int rowblk = blockIdx.x & 31;
  bool isin = (g < Pc);
  int b = base + (isin ? g : g - Pc);
  const float* src = (isin ? in0 : in1) + (size_t)b * IMG;
  float* outhalf = outp + (isin ? (size_t)0 : (size_t)NB*EL*1024) + (size_t)b * EL * 1024;
  float2* P = cplx + (size_t)g * IMG;
  float2* buf = xbuf[wave];
  for (int i=0;i<4;++i){
    int yrow = rowblk*16 + wave*4 + i;
    const float* s = src + (size_t)yrow*EL;
    float2 v[8];
    #pragma unroll
    for (int a=0;a<8;++a){
      float xv = s[64*a + lane];
      outhalf[(size_t)yrow*1024 + 64*a + lane] = xv;   // concat left half = raw input
      float m = __expf(-8.0f * xv * xv);               // soft_equality(x,0,0.25)
      v[a] = make_float2(m, 0.f);
    }
    fft512<-1>(v, buf, lane);
    #pragma unroll
    for (int a=0;a<8;++a)
      P[(size_t)yrow*EL + 64*a + lane] = v[a];         // 512B coalesced
  }
}

// columns: fwd FFT -> |F|^2 (registers) -> inverse FFT.
// 8-col x 512-row tile, slot stride 580; each column's slot doubles as the
// wave's FFT scratch (wave owns its 4 columns exclusively).
__global__ __launch_bounds__(128)
void k_col(float2* __restrict__ cplx){
  __shared__ float2 tile[8*580];
  int l = threadIdx.x;
  int wave = l >> 6, lane = l & 63;
  int g = blockIdx.x >> 6;
  int t = blockIdx.x & 63;
  int c0 = t*8;
  float2* P = cplx + (size_t)g*IMG;
  {
    int cp = l & 3;              // column pair
    int rb = l >> 2;             // 32 rows per iteration
    for (int it=0; it<16; ++it){
      int r = rb + it*32;
      float4 v = *(const float4*)(P + (size_t)r*EL + c0 + 2*cp);  // 64B/row full line
      tile[(2*cp+0)*580 + r] = make_float2(v.x, v.y);
      tile[(2*cp+1)*580 + r] = make_float2(v.z, v.w);
    }
  }
  __syncthreads();
  for (int cc=0; cc<4; ++cc){
    int c = wave*4 + cc;
    float2* slot = &tile[c*580];
    float2 v[8];
    #pragma unroll
    for (int a=0;a<8;++a) v[a] = slot[64*a + lane];
    fft512<-1>(v, slot, lane);                         // slot becomes scratch
    #pragma unroll
    for (int a=0;a<8;++a)
      v[a] = make_float2(v[a].x*v[a].x + v[a].y*v[a].y, 0.f);  // |F|^2
    fft512<1>(v, slot, lane);
    sb();
    #pragma unroll
    for (int a=0;a<8;++a) slot[64*a + lane] = v[a];
  }
  __syncthreads();
  {
    int cp = l & 3;
    int rb = l >> 2;
    for (int it=0; it<16; ++it){
      int r = rb + it*32;
      float2 e0 = tile[(2*cp+0)*580 + r];
      float2 e1 = tile[(2*cp+1)*580 + r];
      *(float4*)(P + (size_t)r*EL + c0 + 2*cp) = make_float4(e0.x, e0.y, e1.x, e1.y);
    }
  }
}

// rows: inverse FFT -> real ac (scaled); fused min/max; compact scrambled
// in-place store: block (g,rb) writes its 16 ac rows (2KB each) into the
// FIRST HALF of the 64KB cplx region it just read (rows interleave as
// offset = rb*16K + (row&15)*512 floats). Single block barrier orders
// all reads before any write.
__global__ __launch_bounds__(256)
void k_row_inv(float2* __restrict__ cplx,
               unsigned* __restrict__ umin, unsigned* __restrict__ umax,
               int base, int Pc){
  __shared__ float2 xbuf[4][576];
  __shared__ float redmn[4], redmx[4];
  int wave = threadIdx.x >> 6, lane = threadIdx.x & 63;
  int g = blockIdx.x >> 5;
  int rowblk = blockIdx.x & 31;
  float2* P = cplx + (size_t)g*IMG;
  float* acb = (float*)P;
  float2* buf = xbuf[wave];
  const float SCALE = 1.0f / 68719476736.0f;   // 2^-36 : ifft2 norm * 1/(el*el)
  float mn = 3.4e38f, mx = -3.4e38f;
  float o[4][8];
  for (int i=0;i<4;++i){
    int yrow = rowblk*16 + wave*4 + i;
    float2 v[8];
    #pragma unroll
    for (int a=0;a<8;++a) v[a] = P[(size_t)yrow*EL + 64*a + lane];
    fft512<1>(v, buf, lane);
    #pragma unroll
    for (int a=0;a<8;++a){
      float ov = v[a].x * SCALE;
      o[i][a] = ov;
      mn = fminf(mn, ov); mx = fmaxf(mx, ov);
    }
  }
  for (int off=32; off>0; off>>=1){
    mn = fminf(mn, __shfl_down(mn, off, 64));
    mx = fmaxf(mx, __shfl_down(mx, off, 64));
  }
  if (lane==0){ redmn[wave]=mn; redmx[wave]=mx; }
  __syncthreads();      // all rows read into registers; redmn/redmx ready
  if (threadIdx.x==0){
    mn = fminf(fminf(redmn[0],redmn[1]), fminf(redmn[2],redmn[3]));
    mx = fmaxf(fmaxf(redmx[0],redmx[1]), fmaxf(redmx[2],redmx[3]));
    int gid = (g < Pc) ? (base + g) : (NB + base + g - Pc);
    atomicMin(&umin[gid], fenc(mn));
    atomicMax(&umax[gid], fenc(mx));
  }
  #pragma unroll
  for (int i=0;i<4;++i){
    int j = wave*4 + i;
    float* dst = acb + (size_t)rowblk*16384 + j*512;
    #pragma unroll
    for (int a=0;a<8;++a) dst[64*a + lane] = o[i][a];
  }
}

// shift + normalize + mask + write right halves + MSE accumulation.
// Reads the scrambled-compact ac layout written by k_row_inv.
__global__ __launch_bounds__(256)
void k_final(const float2* __restrict__ cplx, const unsigned* __restrict__ umin,
             const unsigned* __restrict__ umax, float* __restrict__ outp,
             double* __restrict__ accum, int base, int Pc){
  __shared__ float red[4];
  int g    = blockIdx.x >> 5;      // local pair index [0,Pc)
  int part = blockIdx.x & 31;      // 16-row slice
  int b = base + g;
  float mni = fdec(umin[b]),      mxi = fdec(umax[b]);
  float mnt = fdec(umin[NB + b]), mxt = fdec(umax[NB + b]);
  float inv_i = 1.0f / (mxi - mni + 1e-12f);
  float inv_t = 1.0f / (mxt - mnt + 1e-12f);
  const float* ai_b = (const float*)(cplx + (size_t)g * IMG);
  const float* at_b = (const float*)(cplx + (size_t)(Pc + g) * IMG);
  float* o_i = outp;
  float* o_t = outp + (size_t)NB * 512 * 1024;
  float acc = 0.f;
  for (int it=0; it<8; ++it){
    int q = it*256 + threadIdx.x;        // [0,2048)
    int y = part*16 + (q >> 7);
    int x = (q & 127) * 4;
    int sy = (y + 256) & 511, sx = (x + 256) & 511;   // sx stays 4-aligned
    size_t srow = (size_t)(sy >> 4)*16384 + (size_t)(sy & 15)*512;  // scrambled row base
    float4 ai = *(const float4*)(ai_b + srow + sx);
    float4 at = *(const float4*)(at_b + srow + sx);
    float dy = (float)(y - 256); float dy2 = dy*dy;
    float dx0 = (float)(x - 256);
    float m0 = __expf(-((dx0+0)*(dx0+0) + dy2) * 0.00125f);
    float m1 = __expf(-((dx0+1)*(dx0+1) + dy2) * 0.00125f);
    float m2 = __expf(-((dx0+2)*(dx0+2) + dy2) * 0.00125f);
    float m3 = __expf(-((dx0+3)*(dx0+3) + dy2) * 0.00125f);
    float4 oi, ot;
    oi.x = (ai.x - mni)*inv_i*m0; ot.x = (at.x - mnt)*inv_t*m0;
    oi.y = (ai.y - mni)*inv_i*m1; ot.y = (at.y - mnt)*inv_t*m1;
    oi.z = (ai.z - mni)*inv_i*m2; ot.z = (at.z - mnt)*inv_t*m2;
    oi.w = (ai.w - mni)*inv_i*m3; ot.w = (at.w - mnt)*inv_t*m3;
    size_t rowo = ((size_t)b * 512 + (size_t)y) * 1024 + 512 + x;
    *(float4*)(o_i + 1 + rowo) = oi;   // +1: out[0] is the scalar loss
    *(float4*)(o_t + 1 + rowo) = ot;
    float d0 = oi.x - ot.x, d1 = oi.y - ot.y, d2 = oi.z - ot.z, d3 = oi.w - ot.w;
    acc += d0*d0 + d1*d1 + d2*d2 + d3*d3;
  }
  for (int off=32; off>0; off>>=1) acc += __shfl_down(acc, off, 64);
  int wave = threadIdx.x>>6, lane = threadIdx.x&63;
  if (lane==0) red[wave]=acc;
  __syncthreads();
  if (threadIdx.x==0) atomicAdd(accum, (double)(red[0]+red[1]+red[2]+red[3]));
}

__global__ void k_div(const double* accum, float* out0){
  out0[0] = (float)(*accum / 16777216.0);   // mean over 64*512*512
}

// ---------------- launch ----------------
extern "C" void kernel_launch(void* const* d_in, const int* in_sizes, int n_in,
                              void* d_out, int out_size, void* d_ws, size_t ws_size,
                              hipStream_t stream){
  (void)in_sizes; (void)n_in; (void)out_size;
  const float* in0 = (const float*)d_in[0];
  const float* in1 = (const float*)d_in[1];
  float* out = (float*)d_out;
  char* ws = (char*)d_ws;
  double*   accum = (double*)ws;
  unsigned* umin  = (unsigned*)(ws + 512);
  unsigned* umax  = (unsigned*)(ws + 1024);
  float2*   cplx  = (float2*)(ws + 4096);

  size_t avail = ws_size > 4096 ? ws_size - 4096 : 0;
  int P = (int)(avail / (4ull * 1024ull * 1024ull));  // 4 MB per image-pair (cplx in+tgt)
  if (P > NB) P = NB;
  if (P < 1)  P = 1;

  k_init<<<dim3(1), dim3(128), 0, stream>>>(accum, umin, umax);
  float* out1 = out + 1;
  for (int base = 0; base < NB; base += P){
    int Pc = (NB - base < P) ? (NB - base) : P;
    k_row_fwd<<<dim3(2*Pc*32), dim3(256), 0, stream>>>(in0, in1, cplx, out1, base, Pc);
    k_col    <<<dim3(2*Pc*64), dim3(128), 0, stream>>>(cplx);
    k_row_inv<<<dim3(2*Pc*32), dim3(256), 0, stream>>>(cplx, umin, umax, base, Pc);
    k_final  <<<dim3(Pc*32),   dim3(256), 0, stream>>>(cplx, umin, umax, out, accum, base, Pc);
  }
  k_div<<<dim3(1), dim3(1), 0, stream>>>(accum, out);
}